// Round 7
// baseline (97.767 us; speedup 1.0000x reference)
//
#include <hip/hip_runtime.h>
#include <math.h>

#define BB 4
#define NN 4096
#define MM 4096
#define TI 128          // rows per block tile
#define TJC 64          // cols per block tile (shrunk from 128: per-thread frag
                        // 8x4 -> ~50 VGPR working set fits the 64-VGPR/8-wave
                        // budget, so the compiler stops re-reading Y from LDS
                        // every k-iteration, which R6's VGPR=40 proved it did)
#define NTI (NN / TI)   // 32
#define NTJ2 (MM / TJC) // 64

#define L2E100 144.26950408889634f   // 100*log2(e); exp(-100 d) = exp2(-L2E100 d)

// ---------- cross-lane helpers ----------
__device__ __forceinline__ float dpp_sum16(float v) {
    float t;
    t = __int_as_float(__builtin_amdgcn_update_dpp(0, __float_as_int(v), 0x111, 0xF, 0xF, true)); v += t;
    t = __int_as_float(__builtin_amdgcn_update_dpp(0, __float_as_int(v), 0x112, 0xF, 0xF, true)); v += t;
    t = __int_as_float(__builtin_amdgcn_update_dpp(0, __float_as_int(v), 0x114, 0xF, 0xF, true)); v += t;
    t = __int_as_float(__builtin_amdgcn_update_dpp(0, __float_as_int(v), 0x118, 0xF, 0xF, true)); v += t;
    return v;  // total in lane (tx==15)
}
__device__ __forceinline__ float dpp_min16(float v) {
    float t;
    t = __int_as_float(__builtin_amdgcn_update_dpp(__float_as_int(v), __float_as_int(v), 0x111, 0xF, 0xF, false)); v = fminf(v, t);
    t = __int_as_float(__builtin_amdgcn_update_dpp(__float_as_int(v), __float_as_int(v), 0x112, 0xF, 0xF, false)); v = fminf(v, t);
    t = __int_as_float(__builtin_amdgcn_update_dpp(__float_as_int(v), __float_as_int(v), 0x114, 0xF, 0xF, false)); v = fminf(v, t);
    t = __int_as_float(__builtin_amdgcn_update_dpp(__float_as_int(v), __float_as_int(v), 0x118, 0xF, 0xF, false)); v = fminf(v, t);
    return v;  // min in lane (tx==15)
}
__device__ __forceinline__ float bperm(float v, int addr) {
    return __int_as_float(__builtin_amdgcn_ds_bpermute(addr, __float_as_int(v)));
}

// ---------- staging: X=(-2x,|x|^2), Y=(y,|y|^2); d2 = X.Y + (Xw+Yw) ----------
__device__ __forceinline__ float4 stage_x(const float* p) {
    float a = p[0], b = p[1], c = p[2];
    float4 r; r.x = -2.0f * a; r.y = -2.0f * b; r.z = -2.0f * c;
    r.w = fmaf(a, a, fmaf(b, b, c * c));
    return r;
}
__device__ __forceinline__ float4 stage_y(const float* p) {
    float a = p[0], b = p[1], c = p[2];
    float4 r; r.x = a; r.y = b; r.z = c;
    r.w = fmaf(a, a, fmaf(b, b, c * c));
    return r;
}

// ---------- hand-scheduled inner loops (2 pairs per asm block, 2 ILP chains) ----------
__device__ __forceinline__ void p1_pair2(
    float pqA, float pqB, float Xx, float Xy, float Xz,
    float YxA, float YyA, float YzA, float YxB, float YyB, float YzB,
    float& rmin, float& cminA, float& cminB)
{
    asm("v_fmac_f32 %[pqA], %[Xz], %[YzA]\n\t"
        "v_fmac_f32 %[pqB], %[Xz], %[YzB]\n\t"
        "v_fmac_f32 %[pqA], %[Xy], %[YyA]\n\t"
        "v_fmac_f32 %[pqB], %[Xy], %[YyB]\n\t"
        "v_fmac_f32 %[pqA], %[Xx], %[YxA]\n\t"
        "v_fmac_f32 %[pqB], %[Xx], %[YxB]\n\t"
        "v_min_f32 %[rmin], %[rmin], %[pqA]\n\t"
        "v_min_f32 %[cminA], %[cminA], %[pqA]\n\t"
        "v_min_f32 %[rmin], %[rmin], %[pqB]\n\t"
        "v_min_f32 %[cminB], %[cminB], %[pqB]"
        : [pqA]"+v"(pqA), [pqB]"+v"(pqB), [rmin]"+v"(rmin),
          [cminA]"+v"(cminA), [cminB]"+v"(cminB)
        : [Xx]"v"(Xx), [Xy]"v"(Xy), [Xz]"v"(Xz),
          [YxA]"v"(YxA), [YyA]"v"(YyA), [YzA]"v"(YzA),
          [YxB]"v"(YxB), [YyB]"v"(YyB), [YzB]"v"(YzB));
}

// pass2: 26 instr / 2 pairs = 20 VALU + 6 trans.
__device__ __forceinline__ void p2_pair2(
    float pqA, float pqB, float Xx, float Xy, float Xz, float srk,
    float YxA, float YyA, float YzA, float scA,
    float YxB, float YyB, float YzB, float scB,
    float nL,
    float& nr, float& dr, float& ncA, float& dcA, float& ncB, float& dcB)
{
    float dA, dB, eA, eB;
    asm("v_fmac_f32 %[pqA], %[Xz], %[YzA]\n\t"
        "v_fmac_f32 %[pqB], %[Xz], %[YzB]\n\t"
        "v_fmac_f32 %[pqA], %[Xy], %[YyA]\n\t"
        "v_fmac_f32 %[pqB], %[Xy], %[YyB]\n\t"
        "v_fmac_f32 %[pqA], %[Xx], %[YxA]\n\t"
        "v_fmac_f32 %[pqB], %[Xx], %[YxB]\n\t"
        "v_max_f32 %[pqA], 0, %[pqA]\n\t"
        "v_max_f32 %[pqB], 0, %[pqB]\n\t"
        "v_sqrt_f32 %[dA], %[pqA]\n\t"
        "v_sqrt_f32 %[dB], %[pqB]\n\t"
        "v_fma_f32 %[eA], %[dA], %[nL], %[srk]\n\t"
        "v_fma_f32 %[eB], %[dB], %[nL], %[srk]\n\t"
        "v_exp_f32 %[eA], %[eA]\n\t"
        "v_exp_f32 %[eB], %[eB]\n\t"
        "v_fmac_f32 %[nr], %[dA], %[eA]\n\t"
        "v_add_f32 %[dr], %[dr], %[eA]\n\t"
        "v_fmac_f32 %[nr], %[dB], %[eB]\n\t"
        "v_add_f32 %[dr], %[dr], %[eB]\n\t"
        "v_fma_f32 %[eA], %[dA], %[nL], %[scA]\n\t"
        "v_fma_f32 %[eB], %[dB], %[nL], %[scB]\n\t"
        "v_exp_f32 %[eA], %[eA]\n\t"
        "v_exp_f32 %[eB], %[eB]\n\t"
        "v_fmac_f32 %[ncA], %[dA], %[eA]\n\t"
        "v_add_f32 %[dcA], %[dcA], %[eA]\n\t"
        "v_fmac_f32 %[ncB], %[dB], %[eB]\n\t"
        "v_add_f32 %[dcB], %[dcB], %[eB]"
        : [pqA]"+v"(pqA), [pqB]"+v"(pqB),
          [nr]"+v"(nr), [dr]"+v"(dr),
          [ncA]"+v"(ncA), [dcA]"+v"(dcA), [ncB]"+v"(ncB), [dcB]"+v"(dcB),
          [dA]"=&v"(dA), [dB]"=&v"(dB), [eA]"=&v"(eA), [eB]"=&v"(eB)
        : [Xx]"v"(Xx), [Xy]"v"(Xy), [Xz]"v"(Xz), [srk]"v"(srk),
          [YxA]"v"(YxA), [YyA]"v"(YyA), [YzA]"v"(YzA), [scA]"v"(scA),
          [YxB]"v"(YxB), [YyB]"v"(YyB), [YzB]"v"(YzB), [scB]"v"(scB),
          [nL]"s"(nL));
}

// workspace layout (floats): see R1.
__global__ __launch_bounds__(256)
void init_ws_kernel(float* ws, float* out) {
    int idx = blockIdx.x * 256 + threadIdx.x;
    if (idx < 2 * 16384) ws[idx] = 1e30f;
    else if (idx < 6 * 16384) ws[idx] = 0.0f;
    if (idx == 0) out[0] = 0.0f;
}

__global__ __launch_bounds__(256)
void pass1_min(const float* __restrict__ x, const float* __restrict__ y,
               unsigned int* __restrict__ m2_row, unsigned int* __restrict__ m2_col) {
    const int bid = blockIdx.x;
    const int b   = bid / (NTI * NTJ2);
    const int rem = bid % (NTI * NTJ2);
    const int i0  = (rem / NTJ2) * TI;
    const int j0  = (rem % NTJ2) * TJC;

    __shared__ float4 xs4[TI];
    __shared__ float4 ys4[TJC];
    __shared__ float  cm_w[4][TJC];

    const int t = threadIdx.x;
    if (t < TI) xs4[t] = stage_x(&x[(size_t)(b * NN + i0 + t) * 3]);
    else if (t < TI + TJC) ys4[t - TI] = stage_y(&y[(size_t)(b * MM + j0 + (t - TI)) * 3]);
    __syncthreads();

    const int tx = t & 15, ty = t >> 4;
    const int lane = t & 63, wv = t >> 6;
    float4 Y[4]; float cmin[4];
#pragma unroll
    for (int l = 0; l < 4; ++l) { Y[l] = ys4[tx + l * 16]; cmin[l] = 1e30f; }

#pragma unroll
    for (int k = 0; k < 8; ++k) {
        float4 X = xs4[ty + k * 16];
        float rmin = 1e30f;
#pragma unroll
        for (int l = 0; l < 4; l += 2) {
            p1_pair2(X.w + Y[l].w, X.w + Y[l + 1].w, X.x, X.y, X.z,
                     Y[l].x, Y[l].y, Y[l].z, Y[l + 1].x, Y[l + 1].y, Y[l + 1].z,
                     rmin, cmin[l], cmin[l + 1]);
        }
        rmin = dpp_min16(rmin);
        if (tx == 15) atomicMin(&m2_row[b * NN + i0 + ty + k * 16], __float_as_uint(rmin));
    }

    // cols: butterfly across ty within wave (xor16, xor32), per-wave LDS slot,
    // 4-way combine. No LDS atomics.
    const int a16 = (lane ^ 16) << 2, a32 = (lane ^ 32) << 2;
#pragma unroll
    for (int l = 0; l < 4; ++l) {
        float v = cmin[l];
        v = fminf(v, bperm(v, a16));
        v = fminf(v, bperm(v, a32));
        if (lane < 16) cm_w[wv][lane + l * 16] = v;
    }
    __syncthreads();
    if (t < TJC) {
        float m = fminf(fminf(cm_w[0][t], cm_w[1][t]), fminf(cm_w[2][t], cm_w[3][t]));
        atomicMin(&m2_col[b * MM + j0 + t], __float_as_uint(m));
    }
}

__global__ __launch_bounds__(256)
void pass2_acc(const float* __restrict__ x, const float* __restrict__ y,
               const unsigned int* __restrict__ m2_row, const unsigned int* __restrict__ m2_col,
               float* __restrict__ num_r, float* __restrict__ den_r,
               float* __restrict__ num_c, float* __restrict__ den_c) {
    const int bid = blockIdx.x;
    const int b   = bid / (NTI * NTJ2);
    const int rem = bid % (NTI * NTJ2);
    const int i0  = (rem / NTJ2) * TI;
    const int j0  = (rem % NTJ2) * TJC;

    __shared__ float4 xs4[TI];
    __shared__ float4 ys4[TJC];
    __shared__ float  ar[TI];
    __shared__ float  ac[TJC];
    __shared__ float  sn_w[4][TJC];
    __shared__ float  sd_w[4][TJC];

    const int t = threadIdx.x;
    if (t < TI) {
        xs4[t] = stage_x(&x[(size_t)(b * NN + i0 + t) * 3]);
        ar[t]  = L2E100 * __builtin_amdgcn_sqrtf(fmaxf(__uint_as_float(m2_row[b * NN + i0 + t]), 0.0f));
    } else if (t < TI + TJC) {
        int j = t - TI;
        ys4[j] = stage_y(&y[(size_t)(b * MM + j0 + j) * 3]);
        ac[j]  = L2E100 * __builtin_amdgcn_sqrtf(fmaxf(__uint_as_float(m2_col[b * MM + j0 + j]), 0.0f));
    }
    __syncthreads();

    const int tx = t & 15, ty = t >> 4;
    const int lane = t & 63, wv = t >> 6;
    const float nL = -L2E100;

    float4 Y[4]; float sc[4], nc[4], dc[4];
#pragma unroll
    for (int l = 0; l < 4; ++l) {
        Y[l] = ys4[tx + l * 16]; sc[l] = ac[tx + l * 16];
        nc[l] = 0.0f; dc[l] = 0.0f;
    }

#pragma unroll
    for (int k = 0; k < 8; ++k) {
        float4 X = xs4[ty + k * 16];
        float srk = ar[ty + k * 16];
        float nr = 0.0f, dr = 0.0f;
#pragma unroll
        for (int l = 0; l < 4; l += 2) {
            p2_pair2(X.w + Y[l].w, X.w + Y[l + 1].w, X.x, X.y, X.z, srk,
                     Y[l].x, Y[l].y, Y[l].z, sc[l],
                     Y[l + 1].x, Y[l + 1].y, Y[l + 1].z, sc[l + 1], nL,
                     nr, dr, nc[l], dc[l], nc[l + 1], dc[l + 1]);
        }
        float vn = dpp_sum16(nr);
        float vd = dpp_sum16(dr);
        if (tx == 15) {
            atomicAdd(&num_r[b * NN + i0 + ty + k * 16], vn);
            atomicAdd(&den_r[b * NN + i0 + ty + k * 16], vd);
        }
    }

    // cols: butterfly xor16/xor32 within wave, per-wave LDS slot, 4-way combine.
    const int a16 = (lane ^ 16) << 2, a32 = (lane ^ 32) << 2;
#pragma unroll
    for (int l = 0; l < 4; ++l) {
        float vn = nc[l], vd = dc[l];
        vn += bperm(vn, a16); vd += bperm(vd, a16);
        vn += bperm(vn, a32); vd += bperm(vd, a32);
        if (lane < 16) { sn_w[wv][lane + l * 16] = vn; sd_w[wv][lane + l * 16] = vd; }
    }
    __syncthreads();
    if (t < TJC) {
        float ns = (sn_w[0][t] + sn_w[1][t]) + (sn_w[2][t] + sn_w[3][t]);
        float ds = (sd_w[0][t] + sd_w[1][t]) + (sd_w[2][t] + sd_w[3][t]);
        atomicAdd(&num_c[b * MM + j0 + t], ns);
        atomicAdd(&den_c[b * MM + j0 + t], ds);
    }
}

__global__ __launch_bounds__(256)
void finalize_kernel(const float* __restrict__ num_r, const float* __restrict__ den_r,
                     const float* __restrict__ num_c, const float* __restrict__ den_c,
                     float* __restrict__ out) {
    const int gid = blockIdx.x * 256 + threadIdx.x;
    float s = 0.0f;
    for (int idx = gid; idx < BB * NN; idx += 32 * 256) {
        s = fmaf(num_r[idx], __builtin_amdgcn_rcpf(den_r[idx]), s);
        s = fmaf(num_c[idx], __builtin_amdgcn_rcpf(den_c[idx]), s);
    }
#pragma unroll
    for (int m = 1; m < 64; m <<= 1) s += __shfl_xor(s, m);
    __shared__ float wsum[4];
    const int t = threadIdx.x;
    if ((t & 63) == 0) wsum[t >> 6] = s;
    __syncthreads();
    if (t == 0) {
        float v = (wsum[0] + wsum[1] + wsum[2] + wsum[3]) * (1.0f / (float)(BB * NN));
        atomicAdd(out, v);
    }
}

extern "C" void kernel_launch(void* const* d_in, const int* in_sizes, int n_in,
                              void* d_out, int out_size, void* d_ws, size_t ws_size,
                              hipStream_t stream) {
    const float* x = (const float*)d_in[0];
    const float* y = (const float*)d_in[1];
    float* ws = (float*)d_ws;

    unsigned int* m2_row = (unsigned int*)(ws);
    unsigned int* m2_col = (unsigned int*)(ws + 16384);
    float* num_r = ws + 32768;
    float* den_r = ws + 49152;
    float* num_c = ws + 65536;
    float* den_c = ws + 81920;

    hipLaunchKernelGGL(init_ws_kernel, dim3(384), dim3(256), 0, stream, ws, (float*)d_out);
    dim3 grid(BB * NTI * NTJ2);  // 8192 blocks
    hipLaunchKernelGGL(pass1_min, grid, dim3(256), 0, stream, x, y, m2_row, m2_col);
    hipLaunchKernelGGL(pass2_acc, grid, dim3(256), 0, stream,
                       x, y, m2_row, m2_col, num_r, den_r, num_c, den_c);
    hipLaunchKernelGGL(finalize_kernel, dim3(32), dim3(256), 0, stream,
                       num_r, den_r, num_c, den_c, (float*)d_out);
}

// Round 8
// 69.421 us; speedup vs baseline: 1.4083x; 1.4083x over previous
//
#include <hip/hip_runtime.h>
#include <math.h>

#define BB 4
#define NN 4096
#define MM 4096
#define TI 128
#define TJ 128
#define NTI (NN / TI)   // 32
#define NTJ (MM / TJ)   // 32

#define L2E100 144.26950408889634f   // 100*log2(e); exp(-100 d) = exp2(-L2E100 d)

// ---------- cross-lane helpers ----------
__device__ __forceinline__ float dpp_sum16(float v) {
    float t;
    t = __int_as_float(__builtin_amdgcn_update_dpp(0, __float_as_int(v), 0x111, 0xF, 0xF, true)); v += t;
    t = __int_as_float(__builtin_amdgcn_update_dpp(0, __float_as_int(v), 0x112, 0xF, 0xF, true)); v += t;
    t = __int_as_float(__builtin_amdgcn_update_dpp(0, __float_as_int(v), 0x114, 0xF, 0xF, true)); v += t;
    t = __int_as_float(__builtin_amdgcn_update_dpp(0, __float_as_int(v), 0x118, 0xF, 0xF, true)); v += t;
    return v;  // total in lane (tx==15)
}
__device__ __forceinline__ float dpp_min16(float v) {
    float t;
    t = __int_as_float(__builtin_amdgcn_update_dpp(__float_as_int(v), __float_as_int(v), 0x111, 0xF, 0xF, false)); v = fminf(v, t);
    t = __int_as_float(__builtin_amdgcn_update_dpp(__float_as_int(v), __float_as_int(v), 0x112, 0xF, 0xF, false)); v = fminf(v, t);
    t = __int_as_float(__builtin_amdgcn_update_dpp(__float_as_int(v), __float_as_int(v), 0x114, 0xF, 0xF, false)); v = fminf(v, t);
    t = __int_as_float(__builtin_amdgcn_update_dpp(__float_as_int(v), __float_as_int(v), 0x118, 0xF, 0xF, false)); v = fminf(v, t);
    return v;  // min in lane (tx==15)
}
__device__ __forceinline__ float bperm(float v, int addr) {
    return __int_as_float(__builtin_amdgcn_ds_bpermute(addr, __float_as_int(v)));
}

// ---------- staging: X=(-2x,|x|^2), Y=(y,|y|^2); d2 = X.Y + (Xw+Yw) ----------
__device__ __forceinline__ float4 stage_x(const float* p) {
    float a = p[0], b = p[1], c = p[2];
    float4 r; r.x = -2.0f * a; r.y = -2.0f * b; r.z = -2.0f * c;
    r.w = fmaf(a, a, fmaf(b, b, c * c));
    return r;
}
__device__ __forceinline__ float4 stage_y(const float* p) {
    float a = p[0], b = p[1], c = p[2];
    float4 r; r.x = a; r.y = b; r.z = c;
    r.w = fmaf(a, a, fmaf(b, b, c * c));
    return r;
}

// ---------- asm inner blocks with "+v"-THREADED persistent state ----------
// Every persistent value (Y fragment, sc, X, srk) is a read-write operand of
// every consuming asm block: the compiler cannot rematerialize it from LDS
// (R6/R7 showed plain "v" inputs get remat'd -> ds_read in the hot loop,
// VGPR_Count 40/28). pq is computed INSIDE (its operands were a remat hole).

// pass1: 12 instr / 2 pairs.
__device__ __forceinline__ void p1_pair2(
    float& Xx, float& Xy, float& Xz, float& Xw,
    float& YxA, float& YyA, float& YzA, float& YwA,
    float& YxB, float& YyB, float& YzB, float& YwB,
    float& rmin, float& cminA, float& cminB)
{
    float pqA, pqB;
    asm("v_add_f32 %[pqA], %[Xw], %[YwA]\n\t"
        "v_add_f32 %[pqB], %[Xw], %[YwB]\n\t"
        "v_fmac_f32 %[pqA], %[Xz], %[YzA]\n\t"
        "v_fmac_f32 %[pqB], %[Xz], %[YzB]\n\t"
        "v_fmac_f32 %[pqA], %[Xy], %[YyA]\n\t"
        "v_fmac_f32 %[pqB], %[Xy], %[YyB]\n\t"
        "v_fmac_f32 %[pqA], %[Xx], %[YxA]\n\t"
        "v_fmac_f32 %[pqB], %[Xx], %[YxB]\n\t"
        "v_min_f32 %[rmin], %[rmin], %[pqA]\n\t"
        "v_min_f32 %[cminA], %[cminA], %[pqA]\n\t"
        "v_min_f32 %[rmin], %[rmin], %[pqB]\n\t"
        "v_min_f32 %[cminB], %[cminB], %[pqB]"
        : [pqA]"=&v"(pqA), [pqB]"=&v"(pqB),
          [rmin]"+v"(rmin), [cminA]"+v"(cminA), [cminB]"+v"(cminB),
          [Xx]"+v"(Xx), [Xy]"+v"(Xy), [Xz]"+v"(Xz), [Xw]"+v"(Xw),
          [YxA]"+v"(YxA), [YyA]"+v"(YyA), [YzA]"+v"(YzA), [YwA]"+v"(YwA),
          [YxB]"+v"(YxB), [YyB]"+v"(YyB), [YzB]"+v"(YzB), [YwB]"+v"(YwB));
}

// pass2: 28 instr / 2 pairs = 22 VALU + 6 trans.
__device__ __forceinline__ void p2_pair2(
    float& Xx, float& Xy, float& Xz, float& Xw, float& srk,
    float& YxA, float& YyA, float& YzA, float& YwA, float& scA,
    float& YxB, float& YyB, float& YzB, float& YwB, float& scB,
    float nL,
    float& nr, float& dr, float& ncA, float& dcA, float& ncB, float& dcB)
{
    float pqA, pqB, dA, dB, eA, eB;
    asm("v_add_f32 %[pqA], %[Xw], %[YwA]\n\t"
        "v_add_f32 %[pqB], %[Xw], %[YwB]\n\t"
        "v_fmac_f32 %[pqA], %[Xz], %[YzA]\n\t"
        "v_fmac_f32 %[pqB], %[Xz], %[YzB]\n\t"
        "v_fmac_f32 %[pqA], %[Xy], %[YyA]\n\t"
        "v_fmac_f32 %[pqB], %[Xy], %[YyB]\n\t"
        "v_fmac_f32 %[pqA], %[Xx], %[YxA]\n\t"
        "v_fmac_f32 %[pqB], %[Xx], %[YxB]\n\t"
        "v_max_f32 %[pqA], 0, %[pqA]\n\t"
        "v_max_f32 %[pqB], 0, %[pqB]\n\t"
        "v_sqrt_f32 %[dA], %[pqA]\n\t"
        "v_sqrt_f32 %[dB], %[pqB]\n\t"
        "v_fma_f32 %[eA], %[dA], %[nL], %[srk]\n\t"
        "v_fma_f32 %[eB], %[dB], %[nL], %[srk]\n\t"
        "v_exp_f32 %[eA], %[eA]\n\t"
        "v_exp_f32 %[eB], %[eB]\n\t"
        "v_fmac_f32 %[nr], %[dA], %[eA]\n\t"
        "v_add_f32 %[dr], %[dr], %[eA]\n\t"
        "v_fmac_f32 %[nr], %[dB], %[eB]\n\t"
        "v_add_f32 %[dr], %[dr], %[eB]\n\t"
        "v_fma_f32 %[eA], %[dA], %[nL], %[scA]\n\t"
        "v_fma_f32 %[eB], %[dB], %[nL], %[scB]\n\t"
        "v_exp_f32 %[eA], %[eA]\n\t"
        "v_exp_f32 %[eB], %[eB]\n\t"
        "v_fmac_f32 %[ncA], %[dA], %[eA]\n\t"
        "v_add_f32 %[dcA], %[dcA], %[eA]\n\t"
        "v_fmac_f32 %[ncB], %[dB], %[eB]\n\t"
        "v_add_f32 %[dcB], %[dcB], %[eB]"
        : [pqA]"=&v"(pqA), [pqB]"=&v"(pqB), [dA]"=&v"(dA), [dB]"=&v"(dB),
          [eA]"=&v"(eA), [eB]"=&v"(eB),
          [nr]"+v"(nr), [dr]"+v"(dr),
          [ncA]"+v"(ncA), [dcA]"+v"(dcA), [ncB]"+v"(ncB), [dcB]"+v"(dcB),
          [Xx]"+v"(Xx), [Xy]"+v"(Xy), [Xz]"+v"(Xz), [Xw]"+v"(Xw), [srk]"+v"(srk),
          [YxA]"+v"(YxA), [YyA]"+v"(YyA), [YzA]"+v"(YzA), [YwA]"+v"(YwA), [scA]"+v"(scA),
          [YxB]"+v"(YxB), [YyB]"+v"(YyB), [YzB]"+v"(YzB), [YwB]"+v"(YwB), [scB]"+v"(scB)
        : [nL]"s"(nL));
}

// workspace layout (floats): see R1.
__global__ __launch_bounds__(256)
void init_ws_kernel(float* ws, float* out) {
    int idx = blockIdx.x * 256 + threadIdx.x;
    if (idx < 2 * 16384) ws[idx] = 1e30f;
    else if (idx < 6 * 16384) ws[idx] = 0.0f;
    if (idx == 0) out[0] = 0.0f;
}

__global__ __launch_bounds__(256)
void pass1_min(const float* __restrict__ x, const float* __restrict__ y,
               unsigned int* __restrict__ m2_row, unsigned int* __restrict__ m2_col) {
    const int bid = blockIdx.x;
    const int b   = bid / (NTI * NTJ);
    const int rem = bid % (NTI * NTJ);
    const int i0  = (rem / NTJ) * TI;
    const int j0  = (rem % NTJ) * TJ;

    __shared__ float4 xs4[TI];
    __shared__ float4 ys4[TJ];
    __shared__ float  cm_w[4][TJ];

    const int t = threadIdx.x;
    if (t < TI) xs4[t] = stage_x(&x[(size_t)(b * NN + i0 + t) * 3]);
    else        ys4[t - TI] = stage_y(&y[(size_t)(b * MM + j0 + (t - TI)) * 3]);
    __syncthreads();

    const int tx = t & 15, ty = t >> 4;
    const int lane = t & 63, wv = t >> 6;
    float Yx[8], Yy[8], Yz[8], Yw[8], cmin[8];
#pragma unroll
    for (int l = 0; l < 8; ++l) {
        float4 v = ys4[tx + l * 16];
        Yx[l] = v.x; Yy[l] = v.y; Yz[l] = v.z; Yw[l] = v.w;
        cmin[l] = 1e30f;
    }

#pragma unroll
    for (int k = 0; k < 8; ++k) {
        float4 Xv = xs4[ty + k * 16];
        float Xx = Xv.x, Xy = Xv.y, Xz = Xv.z, Xw = Xv.w;
        float rmin = 1e30f;
#pragma unroll
        for (int l = 0; l < 8; l += 2) {
            p1_pair2(Xx, Xy, Xz, Xw,
                     Yx[l], Yy[l], Yz[l], Yw[l],
                     Yx[l+1], Yy[l+1], Yz[l+1], Yw[l+1],
                     rmin, cmin[l], cmin[l + 1]);
        }
        rmin = dpp_min16(rmin);
        if (tx == 15) atomicMin(&m2_row[b * NN + i0 + ty + k * 16], __float_as_uint(rmin));
    }

    const int a16 = (lane ^ 16) << 2, a32 = (lane ^ 32) << 2;
#pragma unroll
    for (int l = 0; l < 8; ++l) {
        float v = cmin[l];
        v = fminf(v, bperm(v, a16));
        v = fminf(v, bperm(v, a32));
        if (lane < 16) cm_w[wv][lane + l * 16] = v;
    }
    __syncthreads();
    if (t < TJ) {
        float m = fminf(fminf(cm_w[0][t], cm_w[1][t]), fminf(cm_w[2][t], cm_w[3][t]));
        atomicMin(&m2_col[b * MM + j0 + t], __float_as_uint(m));
    }
}

__global__ __launch_bounds__(256)
void pass2_acc(const float* __restrict__ x, const float* __restrict__ y,
               const unsigned int* __restrict__ m2_row, const unsigned int* __restrict__ m2_col,
               float* __restrict__ num_r, float* __restrict__ den_r,
               float* __restrict__ num_c, float* __restrict__ den_c) {
    const int bid = blockIdx.x;
    const int b   = bid / (NTI * NTJ);
    const int rem = bid % (NTI * NTJ);
    const int i0  = (rem / NTJ) * TI;
    const int j0  = (rem % NTJ) * TJ;

    __shared__ float4 xs4[TI];
    __shared__ float4 ys4[TJ];
    __shared__ float  ar[TI];
    __shared__ float  ac[TJ];
    __shared__ float  sn_w[4][TJ];
    __shared__ float  sd_w[4][TJ];

    const int t = threadIdx.x;
    if (t < TI) {
        xs4[t] = stage_x(&x[(size_t)(b * NN + i0 + t) * 3]);
        ar[t]  = L2E100 * __builtin_amdgcn_sqrtf(fmaxf(__uint_as_float(m2_row[b * NN + i0 + t]), 0.0f));
    } else {
        int j = t - TI;
        ys4[j] = stage_y(&y[(size_t)(b * MM + j0 + j) * 3]);
        ac[j]  = L2E100 * __builtin_amdgcn_sqrtf(fmaxf(__uint_as_float(m2_col[b * MM + j0 + j]), 0.0f));
    }
    __syncthreads();

    const int tx = t & 15, ty = t >> 4;
    const int lane = t & 63, wv = t >> 6;
    const float nL = -L2E100;

    float Yx[8], Yy[8], Yz[8], Yw[8], sc[8], nc[8], dc[8];
#pragma unroll
    for (int l = 0; l < 8; ++l) {
        float4 v = ys4[tx + l * 16];
        Yx[l] = v.x; Yy[l] = v.y; Yz[l] = v.z; Yw[l] = v.w;
        sc[l] = ac[tx + l * 16];
        nc[l] = 0.0f; dc[l] = 0.0f;
    }

#pragma unroll
    for (int k = 0; k < 8; ++k) {
        float4 Xv = xs4[ty + k * 16];
        float Xx = Xv.x, Xy = Xv.y, Xz = Xv.z, Xw = Xv.w;
        float srk = ar[ty + k * 16];
        float nr = 0.0f, dr = 0.0f;
#pragma unroll
        for (int l = 0; l < 8; l += 2) {
            p2_pair2(Xx, Xy, Xz, Xw, srk,
                     Yx[l], Yy[l], Yz[l], Yw[l], sc[l],
                     Yx[l+1], Yy[l+1], Yz[l+1], Yw[l+1], sc[l+1],
                     nL, nr, dr, nc[l], dc[l], nc[l + 1], dc[l + 1]);
        }
        float vn = dpp_sum16(nr);
        float vd = dpp_sum16(dr);
        if (tx == 15) {
            atomicAdd(&num_r[b * NN + i0 + ty + k * 16], vn);
            atomicAdd(&den_r[b * NN + i0 + ty + k * 16], vd);
        }
    }

    const int a16 = (lane ^ 16) << 2, a32 = (lane ^ 32) << 2;
#pragma unroll
    for (int l = 0; l < 8; ++l) {
        float vn = nc[l], vd = dc[l];
        vn += bperm(vn, a16); vd += bperm(vd, a16);
        vn += bperm(vn, a32); vd += bperm(vd, a32);
        if (lane < 16) { sn_w[wv][lane + l * 16] = vn; sd_w[wv][lane + l * 16] = vd; }
    }
    __syncthreads();
    if (t < TJ) {
        float ns = (sn_w[0][t] + sn_w[1][t]) + (sn_w[2][t] + sn_w[3][t]);
        float ds = (sd_w[0][t] + sd_w[1][t]) + (sd_w[2][t] + sd_w[3][t]);
        atomicAdd(&num_c[b * MM + j0 + t], ns);
        atomicAdd(&den_c[b * MM + j0 + t], ds);
    }
}

__global__ __launch_bounds__(256)
void finalize_kernel(const float* __restrict__ num_r, const float* __restrict__ den_r,
                     const float* __restrict__ num_c, const float* __restrict__ den_c,
                     float* __restrict__ out) {
    const int gid = blockIdx.x * 256 + threadIdx.x;
    float s = 0.0f;
    for (int idx = gid; idx < BB * NN; idx += 32 * 256) {
        s = fmaf(num_r[idx], __builtin_amdgcn_rcpf(den_r[idx]), s);
        s = fmaf(num_c[idx], __builtin_amdgcn_rcpf(den_c[idx]), s);
    }
#pragma unroll
    for (int m = 1; m < 64; m <<= 1) s += __shfl_xor(s, m);
    __shared__ float wsum[4];
    const int t = threadIdx.x;
    if ((t & 63) == 0) wsum[t >> 6] = s;
    __syncthreads();
    if (t == 0) {
        float v = (wsum[0] + wsum[1] + wsum[2] + wsum[3]) * (1.0f / (float)(BB * NN));
        atomicAdd(out, v);
    }
}

extern "C" void kernel_launch(void* const* d_in, const int* in_sizes, int n_in,
                              void* d_out, int out_size, void* d_ws, size_t ws_size,
                              hipStream_t stream) {
    const float* x = (const float*)d_in[0];
    const float* y = (const float*)d_in[1];
    float* ws = (float*)d_ws;

    unsigned int* m2_row = (unsigned int*)(ws);
    unsigned int* m2_col = (unsigned int*)(ws + 16384);
    float* num_r = ws + 32768;
    float* den_r = ws + 49152;
    float* num_c = ws + 65536;
    float* den_c = ws + 81920;

    hipLaunchKernelGGL(init_ws_kernel, dim3(384), dim3(256), 0, stream, ws, (float*)d_out);
    dim3 grid(BB * NTI * NTJ);  // 4096 blocks
    hipLaunchKernelGGL(pass1_min, grid, dim3(256), 0, stream, x, y, m2_row, m2_col);
    hipLaunchKernelGGL(pass2_acc, grid, dim3(256), 0, stream,
                       x, y, m2_row, m2_col, num_r, den_r, num_c, den_c);
    hipLaunchKernelGGL(finalize_kernel, dim3(32), dim3(256), 0, stream,
                       num_r, den_r, num_c, den_c, (float*)d_out);
}